// Round 6
// baseline (263.703 us; speedup 1.0000x reference)
//
#include <hip/hip_runtime.h>
#include <math.h>

// ---------------- geometry ----------------
constexpr int N  = 167;          // field grid
constexpr int NN = 167 * 167;    // 27889
constexpr int NP = 90;           // input image
constexpr int MP = 84;           // pupil
constexpr int CROP = 120;
constexpr int HCOL = 84;         // Hermitian-reduced column count (t = 0..83)
constexpr int HALF_SZ = 1784896; // (16*167*167*8)/2  for threefry pairing

// ---------------- ws arena (float offsets) ----------------
constexpr size_t SZ_MAT   = (size_t)NN * 2;
constexpr size_t OFF_M1   = 0;
constexpr size_t OFF_M1T  = OFF_M1 + SZ_MAT;
constexpr size_t OFF_WF   = OFF_M1T + SZ_MAT;
constexpr size_t OFF_M2   = OFF_WF + SZ_MAT;
constexpr size_t OFF_M2T  = OFF_M2 + SZ_MAT;
constexpr size_t OFF_M3   = OFF_M2T + SZ_MAT;                  // [120][167] c
constexpr size_t OFF_M3T84= OFF_M3 + (size_t)CROP * N * 2;     // [84][120] c
constexpr size_t OFF_PHI2 = OFF_M3T84 + (size_t)HCOL * CROP * 2; // [167] c
constexpr size_t OFF_AMP  = OFF_PHI2 + (size_t)N * 2;
constexpr size_t OFF_X    = OFF_AMP + 2;                       // [16][167][84] c
constexpr size_t OFF_T1   = OFF_X  + (size_t)16 * N * HCOL * 2;// [16][167][90] c
constexpr size_t OFF_A    = OFF_T1 + (size_t)16 * N * NP * 2;  // [16][167][167] c
constexpr size_t OFF_T2   = OFF_A  + (size_t)16 * NN * 2;      // [16][167][84] c
constexpr size_t OFF_BD   = OFF_T2 + (size_t)16 * N * MP * 2;  // [8][167][167] r
constexpr size_t OFF_T3   = OFF_BD + (size_t)8 * NN;           // [8][167][84] c
constexpr size_t OFF_OTF  = OFF_T3 + (size_t)8 * N * HCOL * 2; // [8][167][84] c
constexpr size_t OFF_FLAT = OFF_OTF+ (size_t)8 * N * HCOL * 2; // [16][12800]
constexpr size_t OFF_PC   = OFF_FLAT + (size_t)16 * 12800;     // [16][84][84] c
constexpr size_t WS_FLOATS = OFF_PC + (size_t)16 * MP * MP * 2;

// ---------------- helpers ----------------
__device__ __forceinline__ unsigned rotl32(unsigned x, int r) {
    return (x << r) | (x >> (32 - r));
}

// jax.random.normal(key(42), [16,167,167,8]) element at flat index idx
__device__ float noise_at(unsigned idx) {
    unsigned c0, c1; int lane;
    if (idx < (unsigned)HALF_SZ) { c0 = idx; c1 = idx + HALF_SZ; lane = 0; }
    else                         { c0 = idx - HALF_SZ; c1 = idx; lane = 1; }
    const unsigned ks0 = 0u, ks1 = 42u, ks2 = 0x1BD11BDAu ^ 42u;
    unsigned x0 = c0 + ks0, x1 = c1 + ks1;
#define TFR(r) { x0 += x1; x1 = rotl32(x1, r); x1 ^= x0; }
    TFR(13) TFR(15) TFR(26) TFR(6)   x0 += ks1; x1 += ks2 + 1u;
    TFR(17) TFR(29) TFR(16) TFR(24)  x0 += ks2; x1 += ks0 + 2u;
    TFR(13) TFR(15) TFR(26) TFR(6)   x0 += ks0; x1 += ks1 + 3u;
    TFR(17) TFR(29) TFR(16) TFR(24)  x0 += ks1; x1 += ks2 + 4u;
    TFR(13) TFR(15) TFR(26) TFR(6)   x0 += ks2; x1 += ks0 + 5u;
#undef TFR
    unsigned bits = lane ? x1 : x0;
    float u01 = __uint_as_float((bits >> 9) | 0x3F800000u) - 1.0f;
    const float lo = -0.99999994f;
    float f = fmaxf(lo, u01 * 2.0f + lo);
    float w = -log1pf(-f * f);
    float p;
    if (w < 5.0f) {
        w -= 2.5f;
        p = 2.81022636e-08f;
        p = fmaf(p, w, 3.43273939e-07f);
        p = fmaf(p, w, -3.5233877e-06f);
        p = fmaf(p, w, -4.39150654e-06f);
        p = fmaf(p, w, 0.00021858087f);
        p = fmaf(p, w, -0.00125372503f);
        p = fmaf(p, w, -0.00417768164f);
        p = fmaf(p, w, 0.246640727f);
        p = fmaf(p, w, 1.50140941f);
    } else {
        w = sqrtf(w) - 3.0f;
        p = -0.000200214257f;
        p = fmaf(p, w, 0.000100950558f);
        p = fmaf(p, w, 0.00134934322f);
        p = fmaf(p, w, -0.00367342844f);
        p = fmaf(p, w, 0.00573950773f);
        p = fmaf(p, w, -0.0076224613f);
        p = fmaf(p, w, 0.00943887047f);
        p = fmaf(p, w, 1.00167406f);
        p = fmaf(p, w, 2.83297682f);
    }
    return 1.41421356237f * p * f;
}

// ---------------- init: disk-mask area ----------------
__global__ void k_amp(float* ws) {
    __shared__ int red[256];
    int t = threadIdx.x, cnt = 0;
    for (int i = t; i < MP * MP; i += 256) {
        int r = i / MP, c = i % MP;
        float y = r - 41.5f, x = c - 41.5f;
        if (x * x + y * y <= 1764.0f) cnt++;
    }
    red[t] = cnt; __syncthreads();
    for (int s = 128; s > 0; s >>= 1) { if (t < s) red[t] += red[t + s]; __syncthreads(); }
    if (t == 0) ws[OFF_AMP] = (float)red[0];
}

// ---------------- init: DFT matrices with folded fftshifts ----------------
__global__ void k_mats(float* ws) {
    int id = blockIdx.x * 256 + threadIdx.x;
    if (id >= NN) return;
    int k = id / N, m = id % N;
    const double TWO_PI = 6.283185307179586476925286766559;
    int t1 = (int)(((long long)(k + 84) * ((m + 83) % N)) % N);
    double a1 = TWO_PI * t1 / (double)N;
    float c1 = (float)cos(a1), s1 = (float)(-sin(a1));
    ws[OFF_M1 + 2 * id] = c1;  ws[OFF_M1 + 2 * id + 1] = s1;
    ws[OFF_M1T + 2 * (m * N + k)] = c1;  ws[OFF_M1T + 2 * (m * N + k) + 1] = s1;
    int tw = (int)(((long long)k * m) % N);
    double aw = TWO_PI * tw / (double)N;
    ws[OFF_WF + 2 * id] = (float)cos(aw);  ws[OFF_WF + 2 * id + 1] = (float)(-sin(aw));
    int t2 = (int)(((long long)(k + 84) * m) % N);
    double a2 = TWO_PI * t2 / (double)N;
    float c2 = (float)(cos(a2) / (double)N), s2 = (float)(sin(a2) / (double)N);
    ws[OFF_M2 + 2 * id] = c2;  ws[OFF_M2 + 2 * id + 1] = s2;
    ws[OFF_M2T + 2 * (m * N + k)] = c2;  ws[OFF_M2T + 2 * (m * N + k) + 1] = s2;
    if (k < CROP) {
        int t3 = (int)(((long long)(k + 108) * ((m + 83) % N)) % N);
        double a3 = TWO_PI * t3 / (double)N;
        float c3 = (float)(cos(a3) / (double)N), s3 = (float)(sin(a3) / (double)N);
        ws[OFF_M3 + 2 * (k * N + m)] = c3;  ws[OFF_M3 + 2 * (k * N + m) + 1] = s3;
        if (m < HCOL) {   // M3T84[nc][j] = M3[j][nc]
            ws[OFF_M3T84 + 2 * (m * CROP + k)] = c3;
            ws[OFF_M3T84 + 2 * (m * CROP + k) + 1] = s3;
        }
    }
    // PHI2[s] = exp(+4*pi*i*s/167)
    if (id < N) {
        double ap = 2.0 * TWO_PI * id / (double)N;
        ws[OFF_PHI2 + 2 * id] = (float)cos(ap);
        ws[OFF_PHI2 + 2 * id + 1] = (float)sin(ap);
    }
}

// ---------------- init: masked pupil field Pc = mask * exp(i*P) ----------------
__global__ void k_pc(const float* __restrict__ P, float* ws) {
    int id = blockIdx.x * 256 + threadIdx.x;
    if (id >= 16 * MP * MP) return;
    int rc = id % (MP * MP);
    int r = rc / MP, c = rc % MP;
    float y = r - 41.5f, x = c - 41.5f;
    float2 v = {0.f, 0.f};
    if (x * x + y * y <= 1764.0f) {
        float sp, cp; sincosf(P[id], &sp, &cp);
        v.x = cp; v.y = sp;
    }
    ((float2*)(ws + OFF_PC))[id] = v;
}

// ---------------- stage 1a: T1 = M1 * xpad (rows) ----------------
__global__ __launch_bounds__(128) void k1a(const float* __restrict__ x, float* ws) {
    int kr = blockIdx.x, b = blockIdx.y, t = threadIdx.x;
    __shared__ float2 m1s[NP];
    const float2* M1 = (const float2*)(ws + OFF_M1);
    if (t < NP) m1s[t] = M1[kr * N + 39 + t];
    __syncthreads();
    if (t >= NP) return;
    float2 acc = {0.f, 0.f};
    for (int nr = 0; nr < NP; nr++) {
        float2 w = m1s[nr];
        float xv = x[(b * NP + nr) * NP + t];
        acc.x += w.x * xv; acc.y += w.y * xv;
    }
    ((float2*)(ws + OFF_T1))[(b * N + kr) * NP + t] = acc;
}

// ---------------- stage 1b: X[:,0..83] = T1 * M1^T (cols, Hermitian-halved) ----------------
__global__ __launch_bounds__(192) void k1b(float* ws) {
    int chunk = blockIdx.x, b = blockIdx.y, tid = threadIdx.x;
    int k0 = chunk * 2;
    __shared__ float2 t1s[2][NP];
    const float2* T1 = (const float2*)(ws + OFF_T1);
    for (int idx = tid; idx < 2 * NP; idx += 192) {
        int r = idx / NP, m = idx % NP;
        if (k0 + r < N) t1s[r][m] = T1[((size_t)b * N + k0 + r) * NP + m];
    }
    __syncthreads();
    int col = tid % HCOL, grp = tid / HCOL;
    if (grp >= 2) return;
    int kr = k0 + grp;
    if (kr >= N) return;
    const float2* M1T = (const float2*)(ws + OFF_M1T);
    float2 acc = {0.f, 0.f};
    for (int nc = 0; nc < NP; nc++) {
        float2 u = t1s[grp][nc];
        float2 w = M1T[(39 + nc) * N + col];
        acc.x += u.x * w.x - u.y * w.y;
        acc.y += u.x * w.y + u.y * w.x;
    }
    ((float2*)(ws + OFF_X))[((size_t)b * N + kr) * HCOL + col] = acc;
}

// ---------------- stage 2a: T2 = F * Pc (rows) ----------------
__global__ __launch_bounds__(128) void k2a(float* ws) {
    int kr = blockIdx.x, j = blockIdx.y, t = threadIdx.x;
    __shared__ float2 wfs[MP];
    const float2* WF = (const float2*)(ws + OFF_WF);
    if (t < MP) wfs[t] = WF[kr * N + 42 + t];
    __syncthreads();
    if (t >= MP) return;
    const float2* PC = (const float2*)(ws + OFF_PC) + (size_t)j * MP * MP;
    float2 acc = {0.f, 0.f};
    for (int nr = 0; nr < MP; nr++) {
        float2 w = wfs[nr];
        float2 pc = PC[nr * MP + t];
        acc.x += w.x * pc.x - w.y * pc.y;
        acc.y += w.x * pc.y + w.y * pc.x;
    }
    ((float2*)(ws + OFF_T2))[(j * N + kr) * MP + t] = acc;
}

// ---------------- stage 2b: A = T2 * F^T (cols, full width) ----------------
constexpr int RCH = 6;
__global__ __launch_bounds__(192) void k2b(float* ws) {
    int chunk = blockIdx.x, j = blockIdx.y, t = threadIdx.x;
    int i0 = chunk * RCH;
    __shared__ float2 t2s[RCH * MP];
    const float2* T2 = (const float2*)(ws + OFF_T2);
    for (int idx = t; idx < RCH * MP; idx += 192) {
        int q = idx / MP, nc = idx % MP, kr = i0 + q;
        if (kr < N) t2s[idx] = T2[(j * N + kr) * MP + nc];
    }
    __syncthreads();
    if (t >= N) return;
    const float2* WF = (const float2*)(ws + OFF_WF);
    float2 acc[RCH];
#pragma unroll
    for (int q = 0; q < RCH; q++) acc[q] = make_float2(0.f, 0.f);
    for (int nc = 0; nc < MP; nc++) {
        float2 w = WF[(42 + nc) * N + t];
#pragma unroll
        for (int q = 0; q < RCH; q++) {
            float2 u = t2s[q * MP + nc];
            acc[q].x += u.x * w.x - u.y * w.y;
            acc[q].y += u.x * w.y + u.y * w.x;
        }
    }
    float2* A = (float2*)(ws + OFF_A);
#pragma unroll
    for (int q = 0; q < RCH; q++)
        if (i0 + q < N) A[((size_t)j * N + i0 + q) * N + t] = acc[q];
}

// Bd[c] = (|A_c|^2 - |A_{c+8}|^2) / amp
__global__ void k_bd(float* ws) {
    int id = blockIdx.x * 256 + threadIdx.x;
    if (id >= 8 * NN) return;
    int c = id / NN, p = id % NN;
    const float2* A = (const float2*)(ws + OFF_A);
    float inv_amp = 1.0f / ws[OFF_AMP];
    float2 a0 = A[(size_t)c * NN + p], a1 = A[(size_t)(c + 8) * NN + p];
    ws[OFF_BD + id] = (a0.x * a0.x + a0.y * a0.y - a1.x * a1.x - a1.y * a1.y) * inv_amp;
}

// ---------------- stage 2c: T3[k, t=0..83] = sum_m Bd[k,m] * M2T[m,t] (cols first) ----------------
__global__ __launch_bounds__(192) void k2c(float* ws) {
    int chunk = blockIdx.x, c = blockIdx.y, tid = threadIdx.x;
    int k0 = chunk * 2;
    __shared__ float bds[2][N];
    const float* BD = ws + OFF_BD + (size_t)c * NN;
    for (int idx = tid; idx < 2 * N; idx += 192) {
        int r = idx / N, m = idx % N;
        if (k0 + r < N) bds[r][m] = BD[(k0 + r) * N + m];
    }
    __syncthreads();
    int col = tid % HCOL, grp = tid / HCOL;
    if (grp >= 2) return;
    int k = k0 + grp;
    if (k >= N) return;
    const float2* M2T = (const float2*)(ws + OFF_M2T);
    float2 acc = {0.f, 0.f};
    for (int m = 0; m < N; m++) {
        float bv = bds[grp][m];
        float2 w = M2T[m * N + col];
        acc.x += w.x * bv; acc.y += w.y * bv;
    }
    ((float2*)(ws + OFF_T3))[((size_t)c * N + k) * HCOL + col] = acc;
}

// ---------------- stage 2d: OTF[i, t=0..83] = sum_k M2[i,k] * T3[k,t] (rows) ----------------
__global__ __launch_bounds__(192) void k2d(float* ws) {
    int chunk = blockIdx.x, c = blockIdx.y, tid = threadIdx.x;
    int i0 = chunk * 2;
    __shared__ float2 m2s[2][N];
    const float2* M2 = (const float2*)(ws + OFF_M2);
    for (int idx = tid; idx < 2 * N; idx += 192) {
        int r = idx / N, k = idx % N;
        if (i0 + r < N) m2s[r][k] = M2[(i0 + r) * N + k];
    }
    __syncthreads();
    int col = tid % HCOL, grp = tid / HCOL;
    if (grp >= 2) return;
    int i = i0 + grp;
    if (i >= N) return;
    const float2* T3 = (const float2*)(ws + OFF_T3) + (size_t)c * N * HCOL;
    float2 acc = {0.f, 0.f};
    for (int k = 0; k < N; k++) {
        float2 w = m2s[grp][k];
        float2 u = T3[k * HCOL + col];
        acc.x += u.x * w.x - u.y * w.y;
        acc.y += u.x * w.y + u.y * w.x;
    }
    ((float2*)(ws + OFF_OTF))[((size_t)c * N + i) * HCOL + col] = acc;
}

// ---------------- stage 3 fused: U rows in LDS -> j-transform -> noise/relu/pool ----------------
// d[i,j] = Re(A) + Re(phi_i*phi_j*A) + Re(B),  A = sum_{t=0..82} U[i,t]M3[j,t], B = U[i,83]M3[j,83]
constexpr int K34R = 6;  // 2 pool rows per block
__global__ __launch_bounds__(192) void k34(float* ws) {
    int chunk = blockIdx.x, c = blockIdx.y, b = blockIdx.z, tid = threadIdx.x;
    int i0 = chunk * K34R;
    __shared__ float2 m3s[K34R * N];     // M3 rows i0..i0+5
    __shared__ float2 us[K34R][HCOL];    // U rows, cols 0..83
    __shared__ float2 phis[N];
    __shared__ float pm[2][CROP];
    const float2* M3 = (const float2*)(ws + OFF_M3);
    const float2* PHI2 = (const float2*)(ws + OFF_PHI2);
    for (int idx = tid; idx < K34R * N; idx += 192) m3s[idx] = M3[i0 * N + idx];
    for (int idx = tid; idx < N; idx += 192) phis[idx] = PHI2[idx];
    __syncthreads();
    // --- phase 1: U[q][col] = sum_kr M3[i0+q,kr] * (X[kr,col]*OTF[kr,col]) ---
    {
        int col = tid % HCOL, grp = tid / HCOL;
        if (grp < 2) {
            const float2* X   = (const float2*)(ws + OFF_X)   + (size_t)b * N * HCOL;
            const float2* OTF = (const float2*)(ws + OFF_OTF) + (size_t)c * N * HCOL;
            const float2* m3r0 = &m3s[(grp * 3 + 0) * N];
            const float2* m3r1 = &m3s[(grp * 3 + 1) * N];
            const float2* m3r2 = &m3s[(grp * 3 + 2) * N];
            float2 a0 = {0.f,0.f}, a1 = {0.f,0.f}, a2 = {0.f,0.f};
            for (int kr = 0; kr < N; kr++) {
                float2 xv = X[kr * HCOL + col], ov = OTF[kr * HCOL + col];
                float2 z;
                z.x = xv.x * ov.x - xv.y * ov.y;
                z.y = xv.x * ov.y + xv.y * ov.x;
                float2 w0 = m3r0[kr], w1 = m3r1[kr], w2 = m3r2[kr];
                a0.x += w0.x * z.x - w0.y * z.y; a0.y += w0.x * z.y + w0.y * z.x;
                a1.x += w1.x * z.x - w1.y * z.y; a1.y += w1.x * z.y + w1.y * z.x;
                a2.x += w2.x * z.x - w2.y * z.y; a2.y += w2.x * z.y + w2.y * z.x;
            }
            us[grp * 3 + 0][col] = a0;
            us[grp * 3 + 1][col] = a1;
            us[grp * 3 + 2][col] = a2;
        }
    }
    __syncthreads();
    // --- phase 2: j-transform + phase fixup + noise + relu + 3-row max ---
    if (tid < CROP) {
        int j = tid;
        const float2* M3T84 = (const float2*)(ws + OFF_M3T84);
        float2 A[K34R];
        float Bq[K34R];
#pragma unroll
        for (int q = 0; q < K34R; q++) A[q] = make_float2(0.f, 0.f);
        for (int nc = 0; nc < HCOL - 1; nc++) {
            float2 w = M3T84[nc * CROP + j];
#pragma unroll
            for (int q = 0; q < K34R; q++) {
                float2 u = us[q][nc];
                A[q].x += u.x * w.x - u.y * w.y;
                A[q].y += u.x * w.y + u.y * w.x;
            }
        }
        {
            float2 w = M3T84[(HCOL - 1) * CROP + j];
#pragma unroll
            for (int q = 0; q < K34R; q++) {
                float2 u = us[q][HCOL - 1];
                Bq[q] = u.x * w.x - u.y * w.y;
            }
        }
#pragma unroll
        for (int g = 0; g < 2; g++) {
            float vmax = 0.f;  // relu folded in
#pragma unroll
            for (int r = 0; r < 3; r++) {
                int q = g * 3 + r, i = i0 + q;
                int s = i + j + 49; if (s >= N) s -= N;   // (i+j+216) mod 167
                float2 ph = phis[s];
                float val = A[q].x * (1.0f + ph.x) - A[q].y * ph.y + Bq[q];
                unsigned idx = (((unsigned)b * N + (24 + i)) * N + (24 + j)) * 8u + c;
                val += 0.003f * noise_at(idx);
                vmax = fmaxf(vmax, val);
            }
            pm[g][j] = vmax;
        }
    }
    __syncthreads();
    if (tid < 40) {
#pragma unroll
        for (int g = 0; g < 2; g++) {
            float m = fmaxf(fmaxf(pm[g][3 * tid], pm[g][3 * tid + 1]), pm[g][3 * tid + 2]);
            int prow = chunk * 2 + g;
            ws[OFF_FLAT + (size_t)b * 12800 + ((size_t)prow * 40 + tid) * 8 + c] = m;
        }
    }
}

// ---------------- stage 4: dense(12800->10) + softmax ----------------
__global__ void k5(const float* __restrict__ W3, const float* __restrict__ b3,
                   const float* __restrict__ ws, float* __restrict__ out) {
    int b = blockIdx.x, t = threadIdx.x;
    __shared__ float red[256][10];
    float acc[10];
#pragma unroll
    for (int o = 0; o < 10; o++) acc[o] = 0.f;
    const float* fl = ws + OFF_FLAT + (size_t)b * 12800;
    for (int f = t; f < 12800; f += 256) {
        float v = fl[f];
#pragma unroll
        for (int o = 0; o < 10; o++) acc[o] = fmaf(v, W3[f * 10 + o], acc[o]);
    }
#pragma unroll
    for (int o = 0; o < 10; o++) red[t][o] = acc[o];
    __syncthreads();
    for (int s = 128; s > 0; s >>= 1) {
        if (t < s) {
#pragma unroll
            for (int o = 0; o < 10; o++) red[t][o] += red[t + s][o];
        }
        __syncthreads();
    }
    if (t == 0) {
        float lg[10], mx = -1e30f;
#pragma unroll
        for (int o = 0; o < 10; o++) { lg[o] = red[0][o] + b3[o]; mx = fmaxf(mx, lg[o]); }
        float sum = 0.f;
#pragma unroll
        for (int o = 0; o < 10; o++) { lg[o] = expf(lg[o] - mx); sum += lg[o]; }
#pragma unroll
        for (int o = 0; o < 10; o++) out[b * 10 + o] = lg[o] / sum;
    }
}

extern "C" void kernel_launch(void* const* d_in, const int* in_sizes, int n_in,
                              void* d_out, int out_size, void* d_ws, size_t ws_size,
                              hipStream_t stream) {
    const float* x  = (const float*)d_in[0];   // [16,90,90,1]
    const float* P  = (const float*)d_in[1];   // [16,84,84]
    const float* W3 = (const float*)d_in[2];   // [12800,10]
    const float* b3 = (const float*)d_in[3];   // [10]
    float* ws  = (float*)d_ws;
    float* out = (float*)d_out;                // [16,10]

    k_amp<<<1, 256, 0, stream>>>(ws);
    k_mats<<<(NN + 255) / 256, 256, 0, stream>>>(ws);
    k_pc<<<(16 * MP * MP + 255) / 256, 256, 0, stream>>>(P, ws);
    k1a<<<dim3(N, 16), 128, 0, stream>>>(x, ws);
    k1b<<<dim3(84, 16), 192, 0, stream>>>(ws);          // 2 rows/block, cols 0..83
    k2a<<<dim3(N, 16), 128, 0, stream>>>(ws);
    k2b<<<dim3((N + RCH - 1) / RCH, 16), 192, 0, stream>>>(ws);
    k_bd<<<(8 * NN + 255) / 256, 256, 0, stream>>>(ws);
    k2c<<<dim3(84, 8), 192, 0, stream>>>(ws);           // 2 rows/block, cols 0..83
    k2d<<<dim3(84, 8), 192, 0, stream>>>(ws);           // 2 rows/block, cols 0..83
    k34<<<dim3(CROP / K34R, 8, 16), 192, 0, stream>>>(ws);
    k5<<<16, 256, 0, stream>>>(W3, b3, ws, out);
}

// Round 7
// 210.692 us; speedup vs baseline: 1.2516x; 1.2516x over previous
//
#include <hip/hip_runtime.h>
#include <math.h>

// ---------------- geometry ----------------
constexpr int N  = 167;          // field grid
constexpr int NN = 167 * 167;    // 27889
constexpr int NP = 90;           // input image
constexpr int MP = 84;           // pupil
constexpr int CROP = 120;
constexpr int HCOL = 84;         // Hermitian-reduced column count (t = 0..83)
constexpr int HALF_SZ = 1784896; // (16*167*167*8)/2  for threefry pairing

// ---------------- ws arena (float offsets) ----------------
constexpr size_t SZ_MAT   = (size_t)NN * 2;
constexpr size_t OFF_M1   = 0;
constexpr size_t OFF_M1T  = OFF_M1 + SZ_MAT;
constexpr size_t OFF_WF   = OFF_M1T + SZ_MAT;
constexpr size_t OFF_M2   = OFF_WF + SZ_MAT;
constexpr size_t OFF_M2T  = OFF_M2 + SZ_MAT;
constexpr size_t OFF_M3   = OFF_M2T + SZ_MAT;                  // [120][167] c
constexpr size_t OFF_M3T84= OFF_M3 + (size_t)CROP * N * 2;     // [84][120] c
constexpr size_t OFF_PHI2 = OFF_M3T84 + (size_t)HCOL * CROP * 2; // [167] c
constexpr size_t OFF_AMP  = OFF_PHI2 + (size_t)N * 2;
constexpr size_t OFF_X    = OFF_AMP + 2;                       // [16][167][84] c
constexpr size_t OFF_T1   = OFF_X  + (size_t)16 * N * HCOL * 2;// [16][167][90] c
constexpr size_t OFF_A    = OFF_T1 + (size_t)16 * N * NP * 2;  // [16][167][167] c
constexpr size_t OFF_T2   = OFF_A  + (size_t)16 * NN * 2;      // [16][167][84] c
constexpr size_t OFF_BD   = OFF_T2 + (size_t)16 * N * MP * 2;  // (unused now)
constexpr size_t OFF_T3   = OFF_BD + (size_t)8 * NN;           // [8][167][84] c
constexpr size_t OFF_OTF  = OFF_T3 + (size_t)8 * N * HCOL * 2; // [8][167][84] c
constexpr size_t OFF_FLAT = OFF_OTF+ (size_t)8 * N * HCOL * 2; // [16][12800]
constexpr size_t OFF_PC   = OFF_FLAT + (size_t)16 * 12800;     // [16][84][84] c
constexpr size_t WS_FLOATS = OFF_PC + (size_t)16 * MP * MP * 2;

// ---------------- helpers ----------------
__device__ __forceinline__ unsigned rotl32(unsigned x, int r) {
    return (x << r) | (x >> (32 - r));
}

// jax.random.normal(key(42), [16,167,167,8]) element at flat index idx
__device__ float noise_at(unsigned idx) {
    unsigned c0, c1; int lane;
    if (idx < (unsigned)HALF_SZ) { c0 = idx; c1 = idx + HALF_SZ; lane = 0; }
    else                         { c0 = idx - HALF_SZ; c1 = idx; lane = 1; }
    const unsigned ks0 = 0u, ks1 = 42u, ks2 = 0x1BD11BDAu ^ 42u;
    unsigned x0 = c0 + ks0, x1 = c1 + ks1;
#define TFR(r) { x0 += x1; x1 = rotl32(x1, r); x1 ^= x0; }
    TFR(13) TFR(15) TFR(26) TFR(6)   x0 += ks1; x1 += ks2 + 1u;
    TFR(17) TFR(29) TFR(16) TFR(24)  x0 += ks2; x1 += ks0 + 2u;
    TFR(13) TFR(15) TFR(26) TFR(6)   x0 += ks0; x1 += ks1 + 3u;
    TFR(17) TFR(29) TFR(16) TFR(24)  x0 += ks1; x1 += ks2 + 4u;
    TFR(13) TFR(15) TFR(26) TFR(6)   x0 += ks2; x1 += ks0 + 5u;
#undef TFR
    unsigned bits = lane ? x1 : x0;
    float u01 = __uint_as_float((bits >> 9) | 0x3F800000u) - 1.0f;
    const float lo = -0.99999994f;
    float f = fmaxf(lo, u01 * 2.0f + lo);
    float w = -log1pf(-f * f);
    float p;
    if (w < 5.0f) {
        w -= 2.5f;
        p = 2.81022636e-08f;
        p = fmaf(p, w, 3.43273939e-07f);
        p = fmaf(p, w, -3.5233877e-06f);
        p = fmaf(p, w, -4.39150654e-06f);
        p = fmaf(p, w, 0.00021858087f);
        p = fmaf(p, w, -0.00125372503f);
        p = fmaf(p, w, -0.00417768164f);
        p = fmaf(p, w, 0.246640727f);
        p = fmaf(p, w, 1.50140941f);
    } else {
        w = sqrtf(w) - 3.0f;
        p = -0.000200214257f;
        p = fmaf(p, w, 0.000100950558f);
        p = fmaf(p, w, 0.00134934322f);
        p = fmaf(p, w, -0.00367342844f);
        p = fmaf(p, w, 0.00573950773f);
        p = fmaf(p, w, -0.0076224613f);
        p = fmaf(p, w, 0.00943887047f);
        p = fmaf(p, w, 1.00167406f);
        p = fmaf(p, w, 2.83297682f);
    }
    return 1.41421356237f * p * f;
}

// ---------------- prep: DFT matrices + pupil field + disk area (one kernel) ----------------
__global__ void k_prep(const float* __restrict__ P, float* ws) {
    int bx = blockIdx.x, t = threadIdx.x;
    if (bx < 109) {
        int id = bx * 256 + t;
        if (id >= NN) return;
        int k = id / N, m = id % N;
        const float TPI = (float)(6.283185307179586476925286766559 / 167.0);
        float s1, c1, sw, cw, s2, c2;
        int t1 = (int)(((long long)(k + 84) * ((m + 83) % N)) % N);
        sincosf(TPI * (float)t1, &s1, &c1);
        ws[OFF_M1 + 2 * id] = c1;  ws[OFF_M1 + 2 * id + 1] = -s1;
        ws[OFF_M1T + 2 * (m * N + k)] = c1;  ws[OFF_M1T + 2 * (m * N + k) + 1] = -s1;
        int tw = (int)(((long long)k * m) % N);
        sincosf(TPI * (float)tw, &sw, &cw);
        ws[OFF_WF + 2 * id] = cw;  ws[OFF_WF + 2 * id + 1] = -sw;
        int t2 = (int)(((long long)(k + 84) * m) % N);
        sincosf(TPI * (float)t2, &s2, &c2);
        const float inv = 1.0f / 167.0f;
        ws[OFF_M2 + 2 * id] = c2 * inv;  ws[OFF_M2 + 2 * id + 1] = s2 * inv;
        ws[OFF_M2T + 2 * (m * N + k)] = c2 * inv;  ws[OFF_M2T + 2 * (m * N + k) + 1] = s2 * inv;
        if (k < CROP) {
            int t3 = (int)(((long long)(k + 108) * ((m + 83) % N)) % N);
            float s3, c3;
            sincosf(TPI * (float)t3, &s3, &c3);
            ws[OFF_M3 + 2 * (k * N + m)] = c3 * inv;  ws[OFF_M3 + 2 * (k * N + m) + 1] = s3 * inv;
            if (m < HCOL) {
                ws[OFF_M3T84 + 2 * (m * CROP + k)] = c3 * inv;
                ws[OFF_M3T84 + 2 * (m * CROP + k) + 1] = s3 * inv;
            }
        }
        if (id < N) {
            int tp = (2 * id) % N;
            float sp, cp;
            sincosf(TPI * (float)tp, &sp, &cp);
            ws[OFF_PHI2 + 2 * id] = cp;
            ws[OFF_PHI2 + 2 * id + 1] = sp;
        }
    } else if (bx < 550) {
        int id = (bx - 109) * 256 + t;
        if (id >= 16 * MP * MP) return;
        int rc = id % (MP * MP);
        int r = rc / MP, c = rc % MP;
        float y = r - 41.5f, x = c - 41.5f;
        float2 v = {0.f, 0.f};
        if (x * x + y * y <= 1764.0f) {
            float sp, cp; sincosf(P[id], &sp, &cp);
            v.x = cp; v.y = sp;
        }
        ((float2*)(ws + OFF_PC))[id] = v;
    } else {
        __shared__ int red[256];
        int cnt = 0;
        for (int i = t; i < MP * MP; i += 256) {
            int r = i / MP, c = i % MP;
            float y = r - 41.5f, x = c - 41.5f;
            if (x * x + y * y <= 1764.0f) cnt++;
        }
        red[t] = cnt; __syncthreads();
        for (int s = 128; s > 0; s >>= 1) { if (t < s) red[t] += red[t + s]; __syncthreads(); }
        if (t == 0) ws[OFF_AMP] = (float)red[0];
    }
}

// ---------------- row transforms: T1 = M1 * xpad  |  T2 = F * Pc ----------------
__global__ __launch_bounds__(128) void k_rows(const float* __restrict__ x, float* ws) {
    int kr = blockIdx.x, bj = blockIdx.y, t = threadIdx.x;
    __shared__ float2 wbuf[NP];
    if (blockIdx.z == 0) {
        const float2* M1 = (const float2*)(ws + OFF_M1);
        if (t < NP) wbuf[t] = M1[kr * N + 39 + t];
        __syncthreads();
        if (t >= NP) return;
        float2 acc = {0.f, 0.f};
        for (int nr = 0; nr < NP; nr++) {
            float2 w = wbuf[nr];
            float xv = x[(bj * NP + nr) * NP + t];
            acc.x += w.x * xv; acc.y += w.y * xv;
        }
        ((float2*)(ws + OFF_T1))[(bj * N + kr) * NP + t] = acc;
    } else {
        const float2* WF = (const float2*)(ws + OFF_WF);
        if (t < MP) wbuf[t] = WF[kr * N + 42 + t];
        __syncthreads();
        if (t >= MP) return;
        const float2* PC = (const float2*)(ws + OFF_PC) + (size_t)bj * MP * MP;
        float2 acc = {0.f, 0.f};
        for (int nr = 0; nr < MP; nr++) {
            float2 w = wbuf[nr];
            float2 pc = PC[nr * MP + t];
            acc.x += w.x * pc.x - w.y * pc.y;
            acc.y += w.x * pc.y + w.y * pc.x;
        }
        ((float2*)(ws + OFF_T2))[(bj * N + kr) * MP + t] = acc;
    }
}

// ---------------- col transforms: X (Hermitian-halved) | A (full) ----------------
constexpr int RCH = 6;
__global__ __launch_bounds__(192) void k_cols(float* ws) {
    int bj = blockIdx.y, tid = threadIdx.x;
    __shared__ float2 sbuf[RCH * MP];   // 504 float2, covers both uses
    if (blockIdx.x < 84) {
        // ---- X[:,0..83] = T1 * M1^T, 2 rows/block ----
        int k0 = blockIdx.x * 2;
        const float2* T1 = (const float2*)(ws + OFF_T1);
        for (int idx = tid; idx < 2 * NP; idx += 192) {
            int r = idx / NP, m = idx % NP;
            if (k0 + r < N) sbuf[r * NP + m] = T1[((size_t)bj * N + k0 + r) * NP + m];
        }
        __syncthreads();
        int col = tid % HCOL, grp = tid / HCOL;
        if (grp >= 2) return;
        int kr = k0 + grp;
        if (kr >= N) return;
        const float2* M1T = (const float2*)(ws + OFF_M1T);
        float2 acc = {0.f, 0.f};
        for (int nc = 0; nc < NP; nc++) {
            float2 u = sbuf[grp * NP + nc];
            float2 w = M1T[(39 + nc) * N + col];
            acc.x += u.x * w.x - u.y * w.y;
            acc.y += u.x * w.y + u.y * w.x;
        }
        ((float2*)(ws + OFF_X))[((size_t)bj * N + kr) * HCOL + col] = acc;
    } else {
        // ---- A = T2 * F^T, 6 rows/block, full 167 cols ----
        int i0 = (blockIdx.x - 84) * RCH;
        const float2* T2 = (const float2*)(ws + OFF_T2);
        for (int idx = tid; idx < RCH * MP; idx += 192) {
            int q = idx / MP, nc = idx % MP, kr = i0 + q;
            if (kr < N) sbuf[idx] = T2[(bj * N + kr) * MP + nc];
        }
        __syncthreads();
        if (tid >= N) return;
        const float2* WF = (const float2*)(ws + OFF_WF);
        float2 acc[RCH];
#pragma unroll
        for (int q = 0; q < RCH; q++) acc[q] = make_float2(0.f, 0.f);
        for (int nc = 0; nc < MP; nc++) {
            float2 w = WF[(42 + nc) * N + tid];
#pragma unroll
            for (int q = 0; q < RCH; q++) {
                float2 u = sbuf[q * MP + nc];
                acc[q].x += u.x * w.x - u.y * w.y;
                acc[q].y += u.x * w.y + u.y * w.x;
            }
        }
        float2* A = (float2*)(ws + OFF_A);
#pragma unroll
        for (int q = 0; q < RCH; q++)
            if (i0 + q < N) A[((size_t)bj * N + i0 + q) * N + tid] = acc[q];
    }
}

// ---------------- stage 2c: T3[k, 0..83] = sum_m Bd[k,m] * M2T[m,t], Bd inline ----------------
__global__ __launch_bounds__(192) void k2c(float* ws) {
    int chunk = blockIdx.x, c = blockIdx.y, tid = threadIdx.x;
    int k0 = chunk * 2;
    __shared__ float bds[2][N];
    const float2* A = (const float2*)(ws + OFF_A);
    float inv_amp = 1.0f / ws[OFF_AMP];
    for (int idx = tid; idx < 2 * N; idx += 192) {
        int r = idx / N, m = idx % N;
        int k = k0 + r;
        if (k < N) {
            float2 a0 = A[((size_t)c * N + k) * N + m];
            float2 a1 = A[((size_t)(c + 8) * N + k) * N + m];
            bds[r][m] = (a0.x * a0.x + a0.y * a0.y - a1.x * a1.x - a1.y * a1.y) * inv_amp;
        }
    }
    __syncthreads();
    int col = tid % HCOL, grp = tid / HCOL;
    if (grp >= 2) return;
    int k = k0 + grp;
    if (k >= N) return;
    const float2* M2T = (const float2*)(ws + OFF_M2T);
    float2 acc = {0.f, 0.f};
    for (int m = 0; m < N; m++) {
        float bv = bds[grp][m];
        float2 w = M2T[m * N + col];
        acc.x += w.x * bv; acc.y += w.y * bv;
    }
    ((float2*)(ws + OFF_T3))[((size_t)c * N + k) * HCOL + col] = acc;
}

// ---------------- stage 2d: OTF[i, 0..83] = sum_k M2[i,k] * T3[k,t] ----------------
__global__ __launch_bounds__(192) void k2d(float* ws) {
    int chunk = blockIdx.x, c = blockIdx.y, tid = threadIdx.x;
    int i0 = chunk * 2;
    __shared__ float2 m2s[2][N];
    const float2* M2 = (const float2*)(ws + OFF_M2);
    for (int idx = tid; idx < 2 * N; idx += 192) {
        int r = idx / N, k = idx % N;
        if (i0 + r < N) m2s[r][k] = M2[(i0 + r) * N + k];
    }
    __syncthreads();
    int col = tid % HCOL, grp = tid / HCOL;
    if (grp >= 2) return;
    int i = i0 + grp;
    if (i >= N) return;
    const float2* T3 = (const float2*)(ws + OFF_T3) + (size_t)c * N * HCOL;
    float2 acc = {0.f, 0.f};
    for (int k = 0; k < N; k++) {
        float2 w = m2s[grp][k];
        float2 u = T3[k * HCOL + col];
        acc.x += u.x * w.x - u.y * w.y;
        acc.y += u.x * w.y + u.y * w.x;
    }
    ((float2*)(ws + OFF_OTF))[((size_t)c * N + i) * HCOL + col] = acc;
}

// ---------------- stage 3 fused: z staged in LDS, 12 rows/block, noise/relu/pool ----------------
constexpr int K34R = 12;   // rows per block (4 pool rows)
constexpr int KCH  = 16;   // kr chunk staged per iteration
__global__ __launch_bounds__(256) void k34(float* ws) {
    int chunk = blockIdx.x, c = blockIdx.y, b = blockIdx.z, tid = threadIdx.x;
    int i0 = chunk * K34R;
    __shared__ __align__(16) float2 zs[KCH][HCOL];
    __shared__ float2 m3c[K34R][KCH];
    __shared__ __align__(16) float2 us[K34R][HCOL];
    __shared__ float2 phis[N];
    __shared__ float pm[4][CROP];
    const float2* M3  = (const float2*)(ws + OFF_M3);
    const float2* X   = (const float2*)(ws + OFF_X)   + (size_t)b * N * HCOL;
    const float2* OTF = (const float2*)(ws + OFF_OTF) + (size_t)c * N * HCOL;
    for (int idx = tid; idx < N; idx += 256) phis[idx] = ((const float2*)(ws + OFF_PHI2))[idx];

    int p = tid % 42, grp = tid / 42;      // phase-1 FMA mapping: 6 groups x 42 col-pairs
    int r0 = grp * 2, r1 = r0 + 1;
    float2 a00 = {0.f,0.f}, a01 = {0.f,0.f}, a10 = {0.f,0.f}, a11 = {0.f,0.f};

    for (int kr0 = 0; kr0 < N; kr0 += KCH) {
        int chn = min(KCH, N - kr0);
        __syncthreads();
        for (int idx = tid; idx < chn * HCOL; idx += 256) {
            int kl = idx / HCOL, col = idx % HCOL;
            float2 xv = X[(kr0 + kl) * HCOL + col];
            float2 ov = OTF[(kr0 + kl) * HCOL + col];
            zs[kl][col] = make_float2(xv.x * ov.x - xv.y * ov.y,
                                      xv.x * ov.y + xv.y * ov.x);
        }
        for (int idx = tid; idx < K34R * KCH; idx += 256) {
            int r = idx / KCH, kl = idx % KCH;
            if (kl < chn) m3c[r][kl] = M3[(i0 + r) * N + kr0 + kl];
        }
        __syncthreads();
        if (grp < 6) {
#pragma unroll 4
            for (int kl = 0; kl < chn; kl++) {
                float4 zz = *(const float4*)&zs[kl][2 * p];
                float2 w0 = m3c[r0][kl], w1 = m3c[r1][kl];
                a00.x += w0.x * zz.x - w0.y * zz.y;  a00.y += w0.x * zz.y + w0.y * zz.x;
                a01.x += w0.x * zz.z - w0.y * zz.w;  a01.y += w0.x * zz.w + w0.y * zz.z;
                a10.x += w1.x * zz.x - w1.y * zz.y;  a10.y += w1.x * zz.y + w1.y * zz.x;
                a11.x += w1.x * zz.z - w1.y * zz.w;  a11.y += w1.x * zz.w + w1.y * zz.z;
            }
        }
    }
    __syncthreads();
    if (grp < 6) {
        us[r0][2 * p] = a00;  us[r0][2 * p + 1] = a01;
        us[r1][2 * p] = a10;  us[r1][2 * p + 1] = a11;
    }
    __syncthreads();
    // --- phase 2: j-transform + phase fixup + noise + relu + 3-row max ---
    if (tid < 240) {
        int grp2 = tid / CROP, j = tid % CROP;
        int rbase = grp2 * 6;
        const float2* M3T84 = (const float2*)(ws + OFF_M3T84);
        float2 A[6]; float Bq[6];
#pragma unroll
        for (int q = 0; q < 6; q++) A[q] = make_float2(0.f, 0.f);
        for (int nc = 0; nc < HCOL - 1; nc++) {
            float2 w = M3T84[nc * CROP + j];
#pragma unroll
            for (int q = 0; q < 6; q++) {
                float2 u = us[rbase + q][nc];
                A[q].x += u.x * w.x - u.y * w.y;
                A[q].y += u.x * w.y + u.y * w.x;
            }
        }
        {
            float2 w = M3T84[(HCOL - 1) * CROP + j];
#pragma unroll
            for (int q = 0; q < 6; q++) {
                float2 u = us[rbase + q][HCOL - 1];
                Bq[q] = u.x * w.x - u.y * w.y;
            }
        }
#pragma unroll
        for (int g = 0; g < 2; g++) {
            float vmax = 0.f;  // relu folded in
#pragma unroll
            for (int r = 0; r < 3; r++) {
                int q = g * 3 + r, i = i0 + rbase + q;
                int s = i + j + 49; if (s >= N) s -= N;   // (i+j+216) mod 167
                float2 ph = phis[s];
                float val = A[q].x * (1.0f + ph.x) - A[q].y * ph.y + Bq[q];
                unsigned idx = (((unsigned)b * N + (24 + i)) * N + (24 + j)) * 8u + c;
                val += 0.003f * noise_at(idx);
                vmax = fmaxf(vmax, val);
            }
            pm[grp2 * 2 + g][j] = vmax;
        }
    }
    __syncthreads();
    if (tid < 160) {
        int pr = tid / 40, pc = tid % 40;
        float m = fmaxf(fmaxf(pm[pr][3 * pc], pm[pr][3 * pc + 1]), pm[pr][3 * pc + 2]);
        int prow = chunk * 4 + pr;
        ws[OFF_FLAT + (size_t)b * 12800 + ((size_t)prow * 40 + pc) * 8 + c] = m;
    }
}

// ---------------- stage 4: dense(12800->10) + softmax ----------------
__global__ void k5(const float* __restrict__ W3, const float* __restrict__ b3,
                   const float* __restrict__ ws, float* __restrict__ out) {
    int b = blockIdx.x, t = threadIdx.x;
    __shared__ float red[256][10];
    float acc[10];
#pragma unroll
    for (int o = 0; o < 10; o++) acc[o] = 0.f;
    const float* fl = ws + OFF_FLAT + (size_t)b * 12800;
    for (int f = t; f < 12800; f += 256) {
        float v = fl[f];
#pragma unroll
        for (int o = 0; o < 10; o++) acc[o] = fmaf(v, W3[f * 10 + o], acc[o]);
    }
#pragma unroll
    for (int o = 0; o < 10; o++) red[t][o] = acc[o];
    __syncthreads();
    for (int s = 128; s > 0; s >>= 1) {
        if (t < s) {
#pragma unroll
            for (int o = 0; o < 10; o++) red[t][o] += red[t + s][o];
        }
        __syncthreads();
    }
    if (t == 0) {
        float lg[10], mx = -1e30f;
#pragma unroll
        for (int o = 0; o < 10; o++) { lg[o] = red[0][o] + b3[o]; mx = fmaxf(mx, lg[o]); }
        float sum = 0.f;
#pragma unroll
        for (int o = 0; o < 10; o++) { lg[o] = expf(lg[o] - mx); sum += lg[o]; }
#pragma unroll
        for (int o = 0; o < 10; o++) out[b * 10 + o] = lg[o] / sum;
    }
}

extern "C" void kernel_launch(void* const* d_in, const int* in_sizes, int n_in,
                              void* d_out, int out_size, void* d_ws, size_t ws_size,
                              hipStream_t stream) {
    const float* x  = (const float*)d_in[0];   // [16,90,90,1]
    const float* P  = (const float*)d_in[1];   // [16,84,84]
    const float* W3 = (const float*)d_in[2];   // [12800,10]
    const float* b3 = (const float*)d_in[3];   // [10]
    float* ws  = (float*)d_ws;
    float* out = (float*)d_out;                // [16,10]

    k_prep<<<551, 256, 0, stream>>>(P, ws);
    k_rows<<<dim3(N, 16, 2), 128, 0, stream>>>(x, ws);
    k_cols<<<dim3(84 + 28, 16), 192, 0, stream>>>(ws);
    k2c<<<dim3(84, 8), 192, 0, stream>>>(ws);
    k2d<<<dim3(84, 8), 192, 0, stream>>>(ws);
    k34<<<dim3(CROP / K34R, 8, 16), 256, 0, stream>>>(ws);
    k5<<<16, 256, 0, stream>>>(W3, b3, ws, out);
}